// Round 2
// baseline (5029.743 us; speedup 1.0000x reference)
//
#include <hip/hip_runtime.h>
#include <math.h>

// ---------------- constants ----------------
#define SCALE_SSILU (1.0f / 0.6f)
#define INV3 0.57735026918962576451f   // 1/sqrt(3)
#define INVH 0.08838834764831844055f   // 1/sqrt(128)

__device__ __forceinline__ float ssilu(float v) {
    return v * SCALE_SSILU / (1.0f + expf(-v));
}
__device__ __forceinline__ float4 ssilu4(float4 v) {
    return make_float4(ssilu(v.x), ssilu(v.y), ssilu(v.z), ssilu(v.w));
}
__device__ __forceinline__ void fmaf4(float4& acc, float a, float4 w) {
    acc.x = fmaf(a, w.x, acc.x);
    acc.y = fmaf(a, w.y, acc.y);
    acc.z = fmaf(a, w.z, acc.z);
    acc.w = fmaf(a, w.w, acc.w);
}
__device__ __forceinline__ float4 f4prod3(float4 a, float4 b) {   // a*b*INV3 componentwise
    return make_float4(a.x * b.x * INV3, a.y * b.y * INV3, a.z * b.z * INV3, a.w * b.w * INV3);
}
__device__ __forceinline__ float4 f4add(float4 a, float4 b) {
    return make_float4(a.x + b.x, a.y + b.y, a.z + b.z, a.w + b.w);
}
__device__ __forceinline__ float4 f4vecn(float4 p1, float4 p2, float4 v, float ud) {
    return make_float4((p1.x * v.x + p2.x * ud) * INVH,
                       (p1.y * v.y + p2.y * ud) * INVH,
                       (p1.z * v.z + p2.z * ud) * INVH,
                       (p1.w * v.w + p2.w * ud) * INVH);
}

// ---------------- kernel 0: per-batch precompute ----------------
// SLW[b] = scalar_l[b] @ W_sl1[128:256] + b_sl1        (B x 128)
// VLW[b][d] = vector_l[b][d] @ W_vl                    (B x 3 x 128)
__global__ __launch_bounds__(128) void k_precomp(
    const float* __restrict__ scalar_l, const float* __restrict__ vector_l,
    const float* __restrict__ Wsl1, const float* __restrict__ bsl1,
    const float* __restrict__ Wvl,
    float* __restrict__ SLW, float* __restrict__ VLW)
{
    const int b = blockIdx.x, t = threadIdx.x;
    __shared__ float sl[128];
    __shared__ float vl[3 * 128];
    sl[t] = scalar_l[b * 128 + t];
    for (int d = 0; d < 3; ++d) vl[d * 128 + t] = vector_l[b * 384 + d * 128 + t];
    __syncthreads();
    float acc = bsl1[t];
    for (int k = 0; k < 128; ++k) acc = fmaf(sl[k], Wsl1[(128 + k) * 128 + t], acc);
    SLW[b * 128 + t] = acc;
    for (int d = 0; d < 3; ++d) {
        float a = 0.f;
        for (int k = 0; k < 128; ++k) a = fmaf(vl[d * 128 + k], Wvl[k * 128 + t], a);
        VLW[b * 384 + d * 128 + t] = a;
    }
}

// ---------------- kernel 1: node part A ----------------
// t1 = ssilu(x @ Wxp1 + bxp1)
// xp = t1 @ Wxp2 + bxp2 ; ep = ef @ Wep + bep ; p = xp*ep/sqrt3 -> (p1,p2,p3)
// xn = p3 + x  -> written to hx region
// vecn[d] = (p1*vec[d] + p2*ud[d]) / sqrt(128) -> written to hvec region
__global__ __launch_bounds__(256) void k_node_a(
    const float* __restrict__ x, const float* __restrict__ vec,
    const float* __restrict__ ef, const float* __restrict__ udiff,
    const float* __restrict__ Wxp1, const float* __restrict__ bxp1,
    const float* __restrict__ Wxp2, const float* __restrict__ bxp2,
    const float* __restrict__ Wep, const float* __restrict__ bep,
    float* __restrict__ xn_out, float* __restrict__ vecn_out, int N)
{
    __shared__ float xs[32 * 132];   // padded stride 132 -> conflict-free column reads
    __shared__ float efs[32 * 68];
    __shared__ float t1s[32 * 132];
    const int t = threadIdx.x;
    const long base = (long)blockIdx.x * 32;

    for (int i = t; i < 1024; i += 256) {          // 32x128 floats as float4
        const int f = i * 4; const int r = f >> 7; const int c = f & 127;
        long n = base + r; if (n > N - 1) n = N - 1;
        *(float4*)&xs[r * 132 + c] = *(const float4*)&x[n * 128 + c];
    }
    for (int i = t; i < 512; i += 256) {           // 32x64 floats as float4
        const int f = i * 4; const int r = f >> 6; const int c = f & 63;
        long n = base + r; if (n > N - 1) n = N - 1;
        *(float4*)&efs[r * 68 + c] = *(const float4*)&ef[n * 64 + c];
    }
    __syncthreads();

    const int r = t >> 3;            // node row within tile: 0..31
    const int c0 = (t & 7) * 16;     // column group start: 0..112
    const int rb = r * 132;

    // phase A: t1 = ssilu(x @ Wxp1 + b), 16 cols/thread
    {
        float4 acc[4];
#pragma unroll
        for (int i = 0; i < 4; ++i) acc[i] = *(const float4*)&bxp1[c0 + 4 * i];
        for (int k = 0; k < 128; ++k) {
            const float a = xs[rb + k];
            const float4* w = (const float4*)&Wxp1[k * 128 + c0];
#pragma unroll
            for (int i = 0; i < 4; ++i) fmaf4(acc[i], a, w[i]);
        }
#pragma unroll
        for (int i = 0; i < 4; ++i) *(float4*)&t1s[rb + c0 + 4 * i] = ssilu4(acc[i]);
    }
    __syncthreads();

    // phase B: three-thirds GEMMs + combine, 8 cols per pass, 2 passes
    const long node = base + r;
    const bool valid = node < (long)N;
    float ud0 = 0.f, ud1 = 0.f, ud2 = 0.f;
    if (valid) {
        const float* u = &udiff[node * 3];
        ud0 = u[0]; ud1 = u[1]; ud2 = u[2];
    }

    for (int half = 0; half < 2; ++half) {
        const int c = c0 + half * 8;
        float4 xa0 = *(const float4*)&bxp2[c];       float4 xa1 = *(const float4*)&bxp2[c + 4];
        float4 xb0 = *(const float4*)&bxp2[128 + c]; float4 xb1 = *(const float4*)&bxp2[132 + c];
        float4 xc0 = *(const float4*)&bxp2[256 + c]; float4 xc1 = *(const float4*)&bxp2[260 + c];
        for (int k = 0; k < 128; ++k) {
            const float a = t1s[rb + k];
            const float* wr = &Wxp2[k * 384 + c];
            fmaf4(xa0, a, *(const float4*)(wr));
            fmaf4(xa1, a, *(const float4*)(wr + 4));
            fmaf4(xb0, a, *(const float4*)(wr + 128));
            fmaf4(xb1, a, *(const float4*)(wr + 132));
            fmaf4(xc0, a, *(const float4*)(wr + 256));
            fmaf4(xc1, a, *(const float4*)(wr + 260));
        }
        float4 ea0 = *(const float4*)&bep[c];       float4 ea1 = *(const float4*)&bep[c + 4];
        float4 eb0 = *(const float4*)&bep[128 + c]; float4 eb1 = *(const float4*)&bep[132 + c];
        float4 ec0 = *(const float4*)&bep[256 + c]; float4 ec1 = *(const float4*)&bep[260 + c];
        for (int k = 0; k < 64; ++k) {
            const float a = efs[r * 68 + k];
            const float* wr = &Wep[k * 384 + c];
            fmaf4(ea0, a, *(const float4*)(wr));
            fmaf4(ea1, a, *(const float4*)(wr + 4));
            fmaf4(eb0, a, *(const float4*)(wr + 128));
            fmaf4(eb1, a, *(const float4*)(wr + 132));
            fmaf4(ec0, a, *(const float4*)(wr + 256));
            fmaf4(ec1, a, *(const float4*)(wr + 260));
        }
        if (valid) {
            const float4 p1a = f4prod3(xa0, ea0), p1b = f4prod3(xa1, ea1);
            const float4 p2a = f4prod3(xb0, eb0), p2b = f4prod3(xb1, eb1);
            const float4 p3a = f4prod3(xc0, ec0), p3b = f4prod3(xc1, ec1);
            const float4 xv0 = *(const float4*)&xs[rb + c];
            const float4 xv1 = *(const float4*)&xs[rb + c + 4];
            *(float4*)&xn_out[node * 128 + c]     = f4add(p3a, xv0);
            *(float4*)&xn_out[node * 128 + c + 4] = f4add(p3b, xv1);
#pragma unroll
            for (int d = 0; d < 3; ++d) {
                const float udd = (d == 0) ? ud0 : (d == 1) ? ud1 : ud2;
                const float* vrow = &vec[(node * 3 + d) * 128 + c];
                const float4 v0 = *(const float4*)(vrow);
                const float4 v1 = *(const float4*)(vrow + 4);
                *(float4*)&vecn_out[(node * 3 + d) * 128 + c]     = f4vecn(p1a, p2a, v0, udd);
                *(float4*)&vecn_out[(node * 3 + d) * 128 + c + 4] = f4vecn(p1b, p2b, v1, udd);
            }
        }
    }
}

// ---------------- kernel 2a: hx (in-place over xn region) ----------------
// t = ssilu(xn @ Wsl1[:128] + SLW[batch]) ; hx = ssilu(t @ Wsl2 + bsl2) + xn
__global__ __launch_bounds__(256) void k_node_x(
    const float* __restrict__ SLW, const int* __restrict__ batch,
    const float* __restrict__ Wsl1, const float* __restrict__ Wsl2,
    const float* __restrict__ bsl2,
    float* __restrict__ hx, int N)
{
    __shared__ float xs[32 * 132];
    __shared__ float ts[32 * 132];
    __shared__ int bidx[32];
    const int t = threadIdx.x;
    const long base = (long)blockIdx.x * 32;
    for (int i = t; i < 1024; i += 256) {
        const int f = i * 4; const int r = f >> 7; const int c = f & 127;
        long n = base + r; if (n > N - 1) n = N - 1;
        *(float4*)&xs[r * 132 + c] = *(const float4*)&hx[n * 128 + c];
    }
    if (t < 32) { long n = base + t; if (n > N - 1) n = N - 1; bidx[t] = batch[n]; }
    __syncthreads();

    const int r = t >> 3, c0 = (t & 7) * 16, rb = r * 132;
    const int bi = bidx[r];
    {
        float4 acc[4];
        const float4* s = (const float4*)&SLW[bi * 128 + c0];
#pragma unroll
        for (int i = 0; i < 4; ++i) acc[i] = s[i];
        for (int k = 0; k < 128; ++k) {
            const float a = xs[rb + k];
            const float4* w = (const float4*)&Wsl1[k * 128 + c0];
#pragma unroll
            for (int i = 0; i < 4; ++i) fmaf4(acc[i], a, w[i]);
        }
#pragma unroll
        for (int i = 0; i < 4; ++i) *(float4*)&ts[rb + c0 + 4 * i] = ssilu4(acc[i]);
    }
    __syncthreads();
    {
        float4 acc[4];
#pragma unroll
        for (int i = 0; i < 4; ++i) acc[i] = *(const float4*)&bsl2[c0 + 4 * i];
        for (int k = 0; k < 128; ++k) {
            const float a = ts[rb + k];
            const float4* w = (const float4*)&Wsl2[k * 128 + c0];
#pragma unroll
            for (int i = 0; i < 4; ++i) fmaf4(acc[i], a, w[i]);
        }
        const long node = base + r;
        if (node < (long)N) {
#pragma unroll
            for (int i = 0; i < 4; ++i) {
                const float4 xv = *(const float4*)&xs[rb + c0 + 4 * i];
                *(float4*)&hx[node * 128 + c0 + 4 * i] = f4add(ssilu4(acc[i]), xv);
            }
        }
    }
}

// ---------------- kernel 2b: hvec (in-place over vecn region) ----------------
// hvec[d] = vecn[d] @ Wvl + VLW[batch][d] + vecn[d]
__global__ __launch_bounds__(256) void k_node_v(
    const float* __restrict__ VLW, const int* __restrict__ batch,
    const float* __restrict__ Wvl,
    float* __restrict__ hv, int N)
{
    __shared__ float vn[96 * 132];   // 32 nodes x 3 dims, padded
    __shared__ int bidx[32];
    const int t = threadIdx.x;
    const long base = (long)blockIdx.x * 32;
    for (int i = t; i < 3072; i += 256) {
        const int f = i * 4;
        const int r = f / 384; const int rem = f - r * 384;
        const int d = rem >> 7; const int c = rem & 127;
        long n = base + r; if (n > N - 1) n = N - 1;
        *(float4*)&vn[(r * 3 + d) * 132 + c] = *(const float4*)&hv[(n * 3 + d) * 128 + c];
    }
    if (t < 32) { long n = base + t; if (n > N - 1) n = N - 1; bidx[t] = batch[n]; }
    __syncthreads();

    const int r = t >> 3, c0 = (t & 7) * 16;
    const long node = base + r;
    const bool valid = node < (long)N;
    const int bi = bidx[r];
    for (int d = 0; d < 3; ++d) {
        const int vb = (r * 3 + d) * 132;
        float4 acc[4];
        const float4* vw = (const float4*)&VLW[bi * 384 + d * 128 + c0];
#pragma unroll
        for (int i = 0; i < 4; ++i) acc[i] = vw[i];
        for (int k = 0; k < 128; ++k) {
            const float a = vn[vb + k];
            const float4* w = (const float4*)&Wvl[k * 128 + c0];
#pragma unroll
            for (int i = 0; i < 4; ++i) fmaf4(acc[i], a, w[i]);
        }
        if (valid) {
#pragma unroll
            for (int i = 0; i < 4; ++i) {
                const float4 vv = *(const float4*)&vn[vb + c0 + 4 * i];
                *(float4*)&hv[(node * 3 + d) * 128 + c0 + 4 * i] = f4add(acc[i], vv);
            }
        }
    }
}

// ---------------- kernel 3: segment means ----------------
__device__ __forceinline__ int lbound(const int* __restrict__ a, int n, int v) {
    int lo = 0, hi = n;
    while (lo < hi) { int m = (lo + hi) >> 1; if (a[m] < v) lo = m + 1; else hi = m; }
    return lo;
}
__global__ __launch_bounds__(256) void k_seg(
    const float* __restrict__ hx, const float* __restrict__ hv,
    const int* __restrict__ batch,
    float* __restrict__ mean_x, float* __restrict__ mean_vec, int N)
{
    const int b = blockIdx.x, t = threadIdx.x;
    const int s = lbound(batch, N, b);
    const int e = lbound(batch, N, b + 1);
    float acc0 = 0.f, acc1 = 0.f;
    for (int i = s; i < e; ++i) {
        const float v0 = (t < 128) ? hx[(long)i * 128 + t] : hv[(long)i * 384 + (t - 128)];
        const float v1 = hv[(long)i * 384 + (t + 128)];
        acc0 += v0; acc1 += v1;
    }
    int cnt = e - s; if (cnt < 1) cnt = 1;
    const float inv = 1.0f / (float)cnt;
    if (t < 128) mean_x[b * 128 + t] = acc0 * inv;
    else         mean_vec[b * 384 + (t - 128)] = acc0 * inv;
    mean_vec[b * 384 + t + 128] = acc1 * inv;
}

// ---------------- kernel 4: global (B rows) ----------------
__global__ __launch_bounds__(128) void k_global(
    const float* __restrict__ mean_x, const float* __restrict__ mean_vec,
    const float* __restrict__ scalar_l, const float* __restrict__ vector_l,
    const float* __restrict__ Wsg1, const float* __restrict__ bsg1,
    const float* __restrict__ Wsg2, const float* __restrict__ bsg2,
    const float* __restrict__ Wvg, const float* __restrict__ Wvp,
    const float* __restrict__ Wlp1, const float* __restrict__ blp1,
    const float* __restrict__ Wlp2, const float* __restrict__ blp2,
    const float* __restrict__ Wml,
    float* __restrict__ out_sl, float* __restrict__ out_vl, float* __restrict__ out_ld)
{
    const int b = blockIdx.x, t = threadIdx.x;
    __shared__ float g[256];
    __shared__ float mv[384];
    __shared__ float sl[128];
    __shared__ float vl[384];
    __shared__ float h1[384];
    __shared__ float vnorm[128];
    __shared__ float t2[128];
    __shared__ float red[128];

    g[t] = mean_x[b * 128 + t];
    const float slin = scalar_l[b * 128 + t];
    g[128 + t] = slin;
    for (int d = 0; d < 3; ++d)
        mv[d * 128 + t] = mean_vec[b * 384 + d * 128 + t] + vector_l[b * 384 + d * 128 + t];
    __syncthreads();

    // tA = ssilu(g @ Wsg1 + b)
    float acc = bsg1[t];
    for (int k = 0; k < 256; ++k) acc = fmaf(g[k], Wsg1[k * 128 + t], acc);
    const float tA = ssilu(acc);
    __syncthreads();          // done reading g
    g[t] = tA;
    __syncthreads();

    // sl = scalar_l + ssilu(tA @ Wsg2 + b)
    acc = bsg2[t];
    for (int k = 0; k < 128; ++k) acc = fmaf(g[k], Wsg2[k * 128 + t], acc);
    sl[t] = slin + ssilu(acc);
    // vl = vector_l + (mean_vec + vector_l) @ Wvg
    for (int d = 0; d < 3; ++d) {
        float a = 0.f;
        for (int k = 0; k < 128; ++k) a = fmaf(mv[d * 128 + k], Wvg[k * 128 + t], a);
        vl[d * 128 + t] = vector_l[b * 384 + d * 128 + t] + a;
    }
    __syncthreads();

    // h1, h2 = split(vl @ Wvp, 2) ; vnorm = sqrt(sum_d h2^2 + 1e-8)
    float hh0 = 0.f, hh1 = 0.f, hh2 = 0.f;
    for (int d = 0; d < 3; ++d) {
        float a1 = 0.f, a2 = 0.f;
        for (int k = 0; k < 128; ++k) {
            const float v = vl[d * 128 + k];
            a1 = fmaf(v, Wvp[k * 256 + t], a1);
            a2 = fmaf(v, Wvp[k * 256 + 128 + t], a2);
        }
        h1[d * 128 + t] = a1;
        if (d == 0) hh0 = a2; else if (d == 1) hh1 = a2; else hh2 = a2;
    }
    vnorm[t] = sqrtf(hh0 * hh0 + hh1 * hh1 + hh2 * hh2 + 1e-8f);
    __syncthreads();

    // t2 = ssilu([sl, vnorm] @ Wlp1 + b)
    acc = blp1[t];
    for (int k = 0; k < 128; ++k) acc = fmaf(sl[k], Wlp1[k * 128 + t], acc);
    for (int k = 0; k < 128; ++k) acc = fmaf(vnorm[k], Wlp1[(128 + k) * 128 + t], acc);
    t2[t] = ssilu(acc);
    __syncthreads();

    // sh = t2 @ Wlp2 + b -> s1, s2, s3
    float s1 = blp2[t], s2 = blp2[128 + t], s3 = blp2[256 + t];
    for (int k = 0; k < 128; ++k) {
        const float v = t2[k];
        s1 = fmaf(v, Wlp2[k * 384 + t], s1);
        s2 = fmaf(v, Wlp2[k * 384 + 128 + t], s2);
        s3 = fmaf(v, Wlp2[k * 384 + 256 + t], s3);
    }
    out_sl[b * 128 + t] = s2 + sl[t] * tanhf(s3);

    const float wm = Wml[t];
    for (int d = 0; d < 3; ++d) {
        const float vo = fmaf(s1, h1[d * 128 + t], vl[d * 128 + t]);
        out_vl[b * 384 + d * 128 + t] = vo;
        red[t] = vo * wm;
        __syncthreads();
        for (int o = 64; o > 0; o >>= 1) {
            if (t < o) red[t] += red[t + o];
            __syncthreads();
        }
        if (t == 0) out_ld[b * 3 + d] = red[0];
        __syncthreads();
    }
}

// ---------------- launch ----------------
extern "C" void kernel_launch(void* const* d_in, const int* in_sizes, int n_in,
                              void* d_out, int out_size, void* d_ws, size_t ws_size,
                              hipStream_t stream)
{
    const float* x         = (const float*)d_in[0];
    const float* scalar_l  = (const float*)d_in[1];
    const float* vec       = (const float*)d_in[2];
    const float* vector_l  = (const float*)d_in[3];
    const float* edge_feat = (const float*)d_in[4];
    const float* edge_ud   = (const float*)d_in[5];
    const int*   batch     = (const int*)d_in[6];
    const float* Wsg1 = (const float*)d_in[7];  const float* bsg1 = (const float*)d_in[8];
    const float* Wsg2 = (const float*)d_in[9];  const float* bsg2 = (const float*)d_in[10];
    const float* Wsl1 = (const float*)d_in[11]; const float* bsl1 = (const float*)d_in[12];
    const float* Wsl2 = (const float*)d_in[13]; const float* bsl2 = (const float*)d_in[14];
    const float* Wvg  = (const float*)d_in[15]; const float* Wvl  = (const float*)d_in[16];
    const float* Wxp1 = (const float*)d_in[17]; const float* bxp1 = (const float*)d_in[18];
    const float* Wxp2 = (const float*)d_in[19]; const float* bxp2 = (const float*)d_in[20];
    const float* Wep  = (const float*)d_in[21]; const float* bep  = (const float*)d_in[22];
    const float* Wvp  = (const float*)d_in[23];
    const float* Wlp1 = (const float*)d_in[24]; const float* blp1 = (const float*)d_in[25];
    const float* Wlp2 = (const float*)d_in[26]; const float* blp2 = (const float*)d_in[27];
    const float* Wml  = (const float*)d_in[28];

    const int N = in_sizes[0] / 128;
    const int B = in_sizes[1] / 128;

    float* out    = (float*)d_out;
    float* hx     = out;                                  // N*128  (holds xn, then hx)
    float* hv     = out + (size_t)N * 128;                // N*384  (holds vecn, then hvec)
    float* out_sl = hv + (size_t)N * 384;                 // B*128
    float* out_vl = out_sl + (size_t)B * 128;             // B*384
    float* out_ld = out_vl + (size_t)B * 384;             // B*3

    float* ws       = (float*)d_ws;
    float* SLW      = ws;                                 // B*128
    float* VLW      = SLW + (size_t)B * 128;              // B*384
    float* mean_x   = VLW + (size_t)B * 384;              // B*128
    float* mean_vec = mean_x + (size_t)B * 128;           // B*384

    const int nblk = (N + 31) / 32;

    k_precomp<<<dim3(B), dim3(128), 0, stream>>>(scalar_l, vector_l, Wsl1, bsl1, Wvl, SLW, VLW);
    k_node_a<<<dim3(nblk), dim3(256), 0, stream>>>(x, vec, edge_feat, edge_ud,
                                                   Wxp1, bxp1, Wxp2, bxp2, Wep, bep, hx, hv, N);
    k_node_x<<<dim3(nblk), dim3(256), 0, stream>>>(SLW, batch, Wsl1, Wsl2, bsl2, hx, N);
    k_node_v<<<dim3(nblk), dim3(256), 0, stream>>>(VLW, batch, Wvl, hv, N);
    k_seg<<<dim3(B), dim3(256), 0, stream>>>(hx, hv, batch, mean_x, mean_vec, N);
    k_global<<<dim3(B), dim3(128), 0, stream>>>(mean_x, mean_vec, scalar_l, vector_l,
                                                Wsg1, bsg1, Wsg2, bsg2, Wvg, Wvp,
                                                Wlp1, blp1, Wlp2, blp2, Wml,
                                                out_sl, out_vl, out_ld);
}

// Round 3
// 1263.626 us; speedup vs baseline: 3.9804x; 3.9804x over previous
//
#include <hip/hip_runtime.h>
#include <math.h>

// ---------------- constants ----------------
#define SCALE_SSILU (1.0f / 0.6f)
#define INV3 0.57735026918962576451f   // 1/sqrt(3)
#define INVH 0.08838834764831844055f   // 1/sqrt(128)

#define ASTRIDE 132      // activation LDS row stride (floats): 132%32=4 -> conflict-free broadcast
#define WSTRIDE 160      // weight LDS row stride: 8 chunks * 20 floats -> 8 disjoint bank groups
#define ESTRIDE 68

__device__ __forceinline__ float ssilu(float v) {
    return v * SCALE_SSILU / (1.0f + __expf(-v));
}
__device__ __forceinline__ float4 ssilu4(float4 v) {
    return make_float4(ssilu(v.x), ssilu(v.y), ssilu(v.z), ssilu(v.w));
}
__device__ __forceinline__ void fmaf4(float4& acc, float a, float4 w) {
    acc.x = fmaf(a, w.x, acc.x);
    acc.y = fmaf(a, w.y, acc.y);
    acc.z = fmaf(a, w.z, acc.z);
    acc.w = fmaf(a, w.w, acc.w);
}
__device__ __forceinline__ float4 f4prod3(float4 a, float4 b) {
    return make_float4(a.x * b.x * INV3, a.y * b.y * INV3, a.z * b.z * INV3, a.w * b.w * INV3);
}
__device__ __forceinline__ float4 f4add(float4 a, float4 b) {
    return make_float4(a.x + b.x, a.y + b.y, a.z + b.z, a.w + b.w);
}
__device__ __forceinline__ float4 f4vecn(float4 p1, float4 p2, float4 v, float ud) {
    return make_float4((p1.x * v.x + p2.x * ud) * INVH,
                       (p1.y * v.y + p2.y * ud) * INVH,
                       (p1.z * v.z + p2.z * ud) * INVH,
                       (p1.w * v.w + p2.w * ud) * INVH);
}

// ---- weight chunk staging: 32 rows x 128 cols, via registers (latency overlap) ----
__device__ __forceinline__ void w_load(const float* __restrict__ W, int LD, int k0, int cofs,
                                       int t, float4 wreg[4]) {
#pragma unroll
    for (int p = 0; p < 4; ++p) {
        const int i = t * 4 + p * 1024;
        const int kk = i >> 7, c = i & 127;
        wreg[p] = *(const float4*)&W[(long)(k0 + kk) * LD + cofs + c];
    }
}
__device__ __forceinline__ void w_store(const float4 wreg[4], float* __restrict__ wbuf, int t) {
#pragma unroll
    for (int p = 0; p < 4; ++p) {
        const int i = t * 4 + p * 1024;
        const int kk = i >> 7, c = i & 127;
        *(float4*)&wbuf[kk * WSTRIDE + (c >> 4) * 20 + (c & 15)] = wreg[p];
    }
}

// ---- 32-k chunk FMA, 2 rows / 3 rows per thread ----
__device__ __forceinline__ void gemm_2r(const float* __restrict__ Abuf, int ra, int rb, int k0,
                                        const float* __restrict__ wbuf, int wc0,
                                        float4 a0[4], float4 a1[4]) {
    for (int kk = 0; kk < 32; ++kk) {
        const float x0 = Abuf[ra + k0 + kk];
        const float x1 = Abuf[rb + k0 + kk];
        const float4* w = (const float4*)&wbuf[kk * WSTRIDE + wc0];
#pragma unroll
        for (int i = 0; i < 4; ++i) { fmaf4(a0[i], x0, w[i]); fmaf4(a1[i], x1, w[i]); }
    }
}
__device__ __forceinline__ void gemm_3r(const float* __restrict__ Abuf, int r0, int r1, int r2, int k0,
                                        const float* __restrict__ wbuf, int wc0,
                                        float4 a0[4], float4 a1[4], float4 a2[4]) {
    for (int kk = 0; kk < 32; ++kk) {
        const float x0 = Abuf[r0 + k0 + kk];
        const float x1 = Abuf[r1 + k0 + kk];
        const float x2 = Abuf[r2 + k0 + kk];
        const float4* w = (const float4*)&wbuf[kk * WSTRIDE + wc0];
#pragma unroll
        for (int i = 0; i < 4; ++i) { fmaf4(a0[i], x0, w[i]); fmaf4(a1[i], x1, w[i]); fmaf4(a2[i], x2, w[i]); }
    }
}

// ---- full GEMM over K = NC*32, weights chunk-staged, reg-double-buffered ----
template<int NC>
__device__ __forceinline__ void run_gemm2(const float* __restrict__ W, int LD, int cofs,
                                          const float* __restrict__ Abuf, int ra, int rb,
                                          float* __restrict__ wbuf, int t, int wc0,
                                          float4 a0[4], float4 a1[4]) {
    float4 wreg[4];
    w_load(W, LD, 0, cofs, t, wreg);
    w_store(wreg, wbuf, t);
    __syncthreads();
#pragma unroll 1
    for (int kc = 0; kc < NC; ++kc) {
        if (kc + 1 < NC) w_load(W, LD, (kc + 1) * 32, cofs, t, wreg);
        gemm_2r(Abuf, ra, rb, kc * 32, wbuf, wc0, a0, a1);
        __syncthreads();
        if (kc + 1 < NC) { w_store(wreg, wbuf, t); __syncthreads(); }
    }
}
template<int NC>
__device__ __forceinline__ void run_gemm3(const float* __restrict__ W, int LD, int cofs,
                                          const float* __restrict__ Abuf, int r0, int r1, int r2,
                                          float* __restrict__ wbuf, int t, int wc0,
                                          float4 a0[4], float4 a1[4], float4 a2[4]) {
    float4 wreg[4];
    w_load(W, LD, 0, cofs, t, wreg);
    w_store(wreg, wbuf, t);
    __syncthreads();
#pragma unroll 1
    for (int kc = 0; kc < NC; ++kc) {
        if (kc + 1 < NC) w_load(W, LD, (kc + 1) * 32, cofs, t, wreg);
        gemm_3r(Abuf, r0, r1, r2, kc * 32, wbuf, wc0, a0, a1, a2);
        __syncthreads();
        if (kc + 1 < NC) { w_store(wreg, wbuf, t); __syncthreads(); }
    }
}

// ---------------- kernel 0: per-batch precompute ----------------
__global__ __launch_bounds__(128) void k_precomp(
    const float* __restrict__ scalar_l, const float* __restrict__ vector_l,
    const float* __restrict__ Wsl1, const float* __restrict__ bsl1,
    const float* __restrict__ Wvl,
    float* __restrict__ SLW, float* __restrict__ VLW)
{
    const int b = blockIdx.x, t = threadIdx.x;
    __shared__ float sl[128];
    __shared__ float vl[3 * 128];
    sl[t] = scalar_l[b * 128 + t];
    for (int d = 0; d < 3; ++d) vl[d * 128 + t] = vector_l[b * 384 + d * 128 + t];
    __syncthreads();
    float acc = bsl1[t];
    for (int k = 0; k < 128; ++k) acc = fmaf(sl[k], Wsl1[(128 + k) * 128 + t], acc);
    SLW[b * 128 + t] = acc;
    for (int d = 0; d < 3; ++d) {
        float a = 0.f;
        for (int k = 0; k < 128; ++k) a = fmaf(vl[d * 128 + k], Wvl[k * 128 + t], a);
        VLW[b * 384 + d * 128 + t] = a;
    }
}

// ---------------- kernel 1: node part A (64 rows/block) ----------------
__global__ __launch_bounds__(256) void k_node_a(
    const float* __restrict__ x, const float* __restrict__ vec,
    const float* __restrict__ ef, const float* __restrict__ udiff,
    const float* __restrict__ Wxp1, const float* __restrict__ bxp1,
    const float* __restrict__ Wxp2, const float* __restrict__ bxp2,
    const float* __restrict__ Wep, const float* __restrict__ bep,
    float* __restrict__ xn_out, float* __restrict__ vecn_out, int N)
{
    __shared__ float A[64 * ASTRIDE];       // x, then t1
    __shared__ float efs[64 * ESTRIDE];
    __shared__ float wbuf[32 * WSTRIDE];
    const int t = threadIdx.x;
    const long base = (long)blockIdx.x * 64;

#pragma unroll
    for (int p = 0; p < 8; ++p) {           // 64x128 x
        const int i = t * 4 + p * 1024;
        const int r = i >> 7, c = i & 127;
        long n = base + r; if (n > N - 1) n = N - 1;
        *(float4*)&A[r * ASTRIDE + c] = *(const float4*)&x[n * 128 + c];
    }
#pragma unroll
    for (int p = 0; p < 4; ++p) {           // 64x64 ef
        const int i = t * 4 + p * 1024;
        const int r = i >> 6, c = i & 63;
        long n = base + r; if (n > N - 1) n = N - 1;
        *(float4*)&efs[r * ESTRIDE + c] = *(const float4*)&ef[n * 64 + c];
    }

    const int cs = t & 7, rs = t >> 3;
    const int c0 = cs * 16, wc0 = cs * 20;
    const int ra = rs * ASTRIDE, rb = (rs + 32) * ASTRIDE;
    const int ea = rs * ESTRIDE, eb = (rs + 32) * ESTRIDE;
    const long nA = base + rs, nB = base + rs + 32;
    const bool vA = nA < (long)N, vB = nB < (long)N;

    float udA[3] = {0.f, 0.f, 0.f}, udB[3] = {0.f, 0.f, 0.f};
    if (vA) { udA[0] = udiff[nA * 3]; udA[1] = udiff[nA * 3 + 1]; udA[2] = udiff[nA * 3 + 2]; }
    if (vB) { udB[0] = udiff[nB * 3]; udB[1] = udiff[nB * 3 + 1]; udB[2] = udiff[nB * 3 + 2]; }

    // ---- phase A: t1 = ssilu(x @ Wxp1 + b) ----
    float4 q0[4], q1[4];
#pragma unroll
    for (int i = 0; i < 4; ++i) { q0[i] = *(const float4*)&bxp1[c0 + 4 * i]; q1[i] = q0[i]; }
    run_gemm2<4>(Wxp1, 128, 0, A, ra, rb, wbuf, t, wc0, q0, q1);   // first sync also covers A/efs staging

    // save x residual (own cols only -> race-free), write t1 back into A
    float4 xsA[4], xsB[4];
#pragma unroll
    for (int i = 0; i < 4; ++i) { xsA[i] = *(const float4*)&A[ra + c0 + 4 * i];
                                  xsB[i] = *(const float4*)&A[rb + c0 + 4 * i]; }
#pragma unroll
    for (int i = 0; i < 4; ++i) { *(float4*)&A[ra + c0 + 4 * i] = ssilu4(q0[i]);
                                  *(float4*)&A[rb + c0 + 4 * i] = ssilu4(q1[i]); }
    __syncthreads();

    // ---- one third: p_j = (t1@Wxp2_j + b) * (ef@Wep_j + b) * inv_sqrt3 ----
    auto do_third = [&](int j, float4 o0[4], float4 o1[4]) {
        float4 e0[4], e1[4];
#pragma unroll
        for (int i = 0; i < 4; ++i) {
            o0[i] = *(const float4*)&bxp2[j * 128 + c0 + 4 * i]; o1[i] = o0[i];
            e0[i] = *(const float4*)&bep [j * 128 + c0 + 4 * i]; e1[i] = e0[i];
        }
        run_gemm2<4>(Wxp2, 384, j * 128, A, ra, rb, wbuf, t, wc0, o0, o1);
        run_gemm2<2>(Wep, 384, j * 128, efs, ea, eb, wbuf, t, wc0, e0, e1);
#pragma unroll
        for (int i = 0; i < 4; ++i) { o0[i] = f4prod3(o0[i], e0[i]); o1[i] = f4prod3(o1[i], e1[i]); }
    };

    // j=2 first: xn = p3 + x (frees xsave early)
    {
        float4 p0[4], p1_[4];
        do_third(2, p0, p1_);
        if (vA) {
#pragma unroll
            for (int i = 0; i < 4; ++i) *(float4*)&xn_out[nA * 128 + c0 + 4 * i] = f4add(p0[i], xsA[i]);
        }
        if (vB) {
#pragma unroll
            for (int i = 0; i < 4; ++i) *(float4*)&xn_out[nB * 128 + c0 + 4 * i] = f4add(p1_[i], xsB[i]);
        }
    }
    // j=0: keep p1
    float4 p1A[4], p1B[4];
    do_third(0, p1A, p1B);
    // j=1: p2, then vecn = (p1*vec + p2*ud)/sqrt(128)
    {
        float4 p2A[4], p2B[4];
        do_third(1, p2A, p2B);
        if (vA) {
#pragma unroll
            for (int d = 0; d < 3; ++d)
#pragma unroll
                for (int i = 0; i < 4; ++i) {
                    const float4 v = *(const float4*)&vec[(nA * 3 + d) * 128 + c0 + 4 * i];
                    *(float4*)&vecn_out[(nA * 3 + d) * 128 + c0 + 4 * i] = f4vecn(p1A[i], p2A[i], v, udA[d]);
                }
        }
        if (vB) {
#pragma unroll
            for (int d = 0; d < 3; ++d)
#pragma unroll
                for (int i = 0; i < 4; ++i) {
                    const float4 v = *(const float4*)&vec[(nB * 3 + d) * 128 + c0 + 4 * i];
                    *(float4*)&vecn_out[(nB * 3 + d) * 128 + c0 + 4 * i] = f4vecn(p1B[i], p2B[i], v, udB[d]);
                }
        }
    }
}

// ---------------- kernel 2a: hx (in-place over xn region, 64 rows/block) ----------------
__global__ __launch_bounds__(256) void k_node_x(
    const float* __restrict__ SLW, const int* __restrict__ batch,
    const float* __restrict__ Wsl1, const float* __restrict__ Wsl2,
    const float* __restrict__ bsl2,
    float* __restrict__ hx, int N)
{
    __shared__ float A[64 * ASTRIDE];
    __shared__ float wbuf[32 * WSTRIDE];
    __shared__ int bidx[64];
    const int t = threadIdx.x;
    const long base = (long)blockIdx.x * 64;

#pragma unroll
    for (int p = 0; p < 8; ++p) {
        const int i = t * 4 + p * 1024;
        const int r = i >> 7, c = i & 127;
        long n = base + r; if (n > N - 1) n = N - 1;
        *(float4*)&A[r * ASTRIDE + c] = *(const float4*)&hx[n * 128 + c];
    }
    if (t < 64) { long n = base + t; if (n > N - 1) n = N - 1; bidx[t] = batch[n]; }
    __syncthreads();

    const int cs = t & 7, rs = t >> 3;
    const int c0 = cs * 16, wc0 = cs * 20;
    const int ra = rs * ASTRIDE, rb = (rs + 32) * ASTRIDE;
    const long nA = base + rs, nB = base + rs + 32;

    // GEMM1: t = ssilu(xn @ Wsl1[:128] + SLW[batch])
    float4 q0[4], q1[4];
    {
        const float4* sA = (const float4*)&SLW[(long)bidx[rs] * 128 + c0];
        const float4* sB = (const float4*)&SLW[(long)bidx[rs + 32] * 128 + c0];
#pragma unroll
        for (int i = 0; i < 4; ++i) { q0[i] = sA[i]; q1[i] = sB[i]; }
    }
    run_gemm2<4>(Wsl1, 128, 0, A, ra, rb, wbuf, t, wc0, q0, q1);

    float4 xsA[4], xsB[4];
#pragma unroll
    for (int i = 0; i < 4; ++i) { xsA[i] = *(const float4*)&A[ra + c0 + 4 * i];
                                  xsB[i] = *(const float4*)&A[rb + c0 + 4 * i]; }
#pragma unroll
    for (int i = 0; i < 4; ++i) { *(float4*)&A[ra + c0 + 4 * i] = ssilu4(q0[i]);
                                  *(float4*)&A[rb + c0 + 4 * i] = ssilu4(q1[i]); }
    __syncthreads();

    // GEMM2: hx = ssilu(t @ Wsl2 + b2) + xn
#pragma unroll
    for (int i = 0; i < 4; ++i) { q0[i] = *(const float4*)&bsl2[c0 + 4 * i]; q1[i] = q0[i]; }
    run_gemm2<4>(Wsl2, 128, 0, A, ra, rb, wbuf, t, wc0, q0, q1);

    if (nA < (long)N) {
#pragma unroll
        for (int i = 0; i < 4; ++i)
            *(float4*)&hx[nA * 128 + c0 + 4 * i] = f4add(ssilu4(q0[i]), xsA[i]);
    }
    if (nB < (long)N) {
#pragma unroll
        for (int i = 0; i < 4; ++i)
            *(float4*)&hx[nB * 128 + c0 + 4 * i] = f4add(ssilu4(q1[i]), xsB[i]);
    }
}

// ---------------- kernel 2b: hvec (in-place over vecn region, 32 nodes/block, d-blocked) -------
__global__ __launch_bounds__(256) void k_node_v(
    const float* __restrict__ VLW, const int* __restrict__ batch,
    const float* __restrict__ Wvl,
    float* __restrict__ hv, int N)
{
    __shared__ float A[96 * ASTRIDE];        // 32 nodes x 3 dims
    __shared__ float wbuf[32 * WSTRIDE];
    __shared__ int bidx[32];
    const int t = threadIdx.x;
    const long base = (long)blockIdx.x * 32;
    const long limit = (long)N * 384 - 4;

#pragma unroll
    for (int p = 0; p < 12; ++p) {           // 32*384 floats
        const int i = t * 4 + p * 1024;
        const int vr = i >> 7, c = i & 127;
        long gi = base * 384 + i; if (gi > limit) gi = limit;
        *(float4*)&A[vr * ASTRIDE + c] = *(const float4*)&hv[gi];
    }
    if (t < 32) { long n = base + t; if (n > N - 1) n = N - 1; bidx[t] = batch[n]; }
    __syncthreads();

    const int cs = t & 7, rs = t >> 3;
    const int c0 = cs * 16, wc0 = cs * 20;
    const int r0 = (rs * 3) * ASTRIDE, r1 = r0 + ASTRIDE, r2 = r1 + ASTRIDE;
    const long n = base + rs;

    float4 a0[4], a1[4], a2[4];
    {
        const float4* w0 = (const float4*)&VLW[(long)bidx[rs] * 384 + c0];
        const float4* w1 = (const float4*)&VLW[(long)bidx[rs] * 384 + 128 + c0];
        const float4* w2 = (const float4*)&VLW[(long)bidx[rs] * 384 + 256 + c0];
#pragma unroll
        for (int i = 0; i < 4; ++i) { a0[i] = w0[i]; a1[i] = w1[i]; a2[i] = w2[i]; }
    }
    run_gemm3<4>(Wvl, 128, 0, A, r0, r1, r2, wbuf, t, wc0, a0, a1, a2);

    if (n < (long)N) {
#pragma unroll
        for (int i = 0; i < 4; ++i) {
            const float4 v0 = *(const float4*)&A[r0 + c0 + 4 * i];
            const float4 v1 = *(const float4*)&A[r1 + c0 + 4 * i];
            const float4 v2 = *(const float4*)&A[r2 + c0 + 4 * i];
            *(float4*)&hv[(n * 3 + 0) * 128 + c0 + 4 * i] = f4add(a0[i], v0);
            *(float4*)&hv[(n * 3 + 1) * 128 + c0 + 4 * i] = f4add(a1[i], v1);
            *(float4*)&hv[(n * 3 + 2) * 128 + c0 + 4 * i] = f4add(a2[i], v2);
        }
    }
}

// ---------------- kernel 3: segment means ----------------
__device__ __forceinline__ int lbound(const int* __restrict__ a, int n, int v) {
    int lo = 0, hi = n;
    while (lo < hi) { int m = (lo + hi) >> 1; if (a[m] < v) lo = m + 1; else hi = m; }
    return lo;
}
__global__ __launch_bounds__(256) void k_seg(
    const float* __restrict__ hx, const float* __restrict__ hv,
    const int* __restrict__ batch,
    float* __restrict__ mean_x, float* __restrict__ mean_vec, int N)
{
    const int b = blockIdx.x, t = threadIdx.x;
    const int s = lbound(batch, N, b);
    const int e = lbound(batch, N, b + 1);
    float a0 = 0.f, a1 = 0.f, a2 = 0.f, a3 = 0.f;
    float c0 = 0.f, c1 = 0.f, c2 = 0.f, c3 = 0.f;
    int i = s;
    for (; i + 4 <= e; i += 4) {
        float v0, v1, v2, v3;
        if (t < 128) {
            v0 = hx[(long)(i + 0) * 128 + t]; v1 = hx[(long)(i + 1) * 128 + t];
            v2 = hx[(long)(i + 2) * 128 + t]; v3 = hx[(long)(i + 3) * 128 + t];
        } else {
            v0 = hv[(long)(i + 0) * 384 + (t - 128)]; v1 = hv[(long)(i + 1) * 384 + (t - 128)];
            v2 = hv[(long)(i + 2) * 384 + (t - 128)]; v3 = hv[(long)(i + 3) * 384 + (t - 128)];
        }
        a0 += v0; a1 += v1; a2 += v2; a3 += v3;
        c0 += hv[(long)(i + 0) * 384 + t + 128]; c1 += hv[(long)(i + 1) * 384 + t + 128];
        c2 += hv[(long)(i + 2) * 384 + t + 128]; c3 += hv[(long)(i + 3) * 384 + t + 128];
    }
    for (; i < e; ++i) {
        a0 += (t < 128) ? hx[(long)i * 128 + t] : hv[(long)i * 384 + (t - 128)];
        c0 += hv[(long)i * 384 + t + 128];
    }
    const float acc0 = (a0 + a1) + (a2 + a3);
    const float acc1 = (c0 + c1) + (c2 + c3);
    int cnt = e - s; if (cnt < 1) cnt = 1;
    const float inv = 1.0f / (float)cnt;
    if (t < 128) mean_x[b * 128 + t] = acc0 * inv;
    else         mean_vec[b * 384 + (t - 128)] = acc0 * inv;
    mean_vec[b * 384 + t + 128] = acc1 * inv;
}

// ---------------- kernel 4: global (B rows) ----------------
__global__ __launch_bounds__(128) void k_global(
    const float* __restrict__ mean_x, const float* __restrict__ mean_vec,
    const float* __restrict__ scalar_l, const float* __restrict__ vector_l,
    const float* __restrict__ Wsg1, const float* __restrict__ bsg1,
    const float* __restrict__ Wsg2, const float* __restrict__ bsg2,
    const float* __restrict__ Wvg, const float* __restrict__ Wvp,
    const float* __restrict__ Wlp1, const float* __restrict__ blp1,
    const float* __restrict__ Wlp2, const float* __restrict__ blp2,
    const float* __restrict__ Wml,
    float* __restrict__ out_sl, float* __restrict__ out_vl, float* __restrict__ out_ld)
{
    const int b = blockIdx.x, t = threadIdx.x;
    __shared__ float g[256];
    __shared__ float mv[384];
    __shared__ float sl[128];
    __shared__ float vl[384];
    __shared__ float h1[384];
    __shared__ float vnorm[128];
    __shared__ float t2[128];
    __shared__ float red[128];

    g[t] = mean_x[b * 128 + t];
    const float slin = scalar_l[b * 128 + t];
    g[128 + t] = slin;
    for (int d = 0; d < 3; ++d)
        mv[d * 128 + t] = mean_vec[b * 384 + d * 128 + t] + vector_l[b * 384 + d * 128 + t];
    __syncthreads();

    float acc = bsg1[t];
    for (int k = 0; k < 256; ++k) acc = fmaf(g[k], Wsg1[k * 128 + t], acc);
    const float tA = ssilu(acc);
    __syncthreads();
    g[t] = tA;
    __syncthreads();

    acc = bsg2[t];
    for (int k = 0; k < 128; ++k) acc = fmaf(g[k], Wsg2[k * 128 + t], acc);
    sl[t] = slin + ssilu(acc);
    for (int d = 0; d < 3; ++d) {
        float a = 0.f;
        for (int k = 0; k < 128; ++k) a = fmaf(mv[d * 128 + k], Wvg[k * 128 + t], a);
        vl[d * 128 + t] = vector_l[b * 384 + d * 128 + t] + a;
    }
    __syncthreads();

    float hh0 = 0.f, hh1 = 0.f, hh2 = 0.f;
    for (int d = 0; d < 3; ++d) {
        float a1 = 0.f, a2 = 0.f;
        for (int k = 0; k < 128; ++k) {
            const float v = vl[d * 128 + k];
            a1 = fmaf(v, Wvp[k * 256 + t], a1);
            a2 = fmaf(v, Wvp[k * 256 + 128 + t], a2);
        }
        h1[d * 128 + t] = a1;
        if (d == 0) hh0 = a2; else if (d == 1) hh1 = a2; else hh2 = a2;
    }
    vnorm[t] = sqrtf(hh0 * hh0 + hh1 * hh1 + hh2 * hh2 + 1e-8f);
    __syncthreads();

    acc = blp1[t];
    for (int k = 0; k < 128; ++k) acc = fmaf(sl[k], Wlp1[k * 128 + t], acc);
    for (int k = 0; k < 128; ++k) acc = fmaf(vnorm[k], Wlp1[(128 + k) * 128 + t], acc);
    t2[t] = ssilu(acc);
    __syncthreads();

    float s1 = blp2[t], s2 = blp2[128 + t], s3 = blp2[256 + t];
    for (int k = 0; k < 128; ++k) {
        const float v = t2[k];
        s1 = fmaf(v, Wlp2[k * 384 + t], s1);
        s2 = fmaf(v, Wlp2[k * 384 + 128 + t], s2);
        s3 = fmaf(v, Wlp2[k * 384 + 256 + t], s3);
    }
    out_sl[b * 128 + t] = s2 + sl[t] * tanhf(s3);

    const float wm = Wml[t];
    for (int d = 0; d < 3; ++d) {
        const float vo = fmaf(s1, h1[d * 128 + t], vl[d * 128 + t]);
        out_vl[b * 384 + d * 128 + t] = vo;
        red[t] = vo * wm;
        __syncthreads();
        for (int o = 64; o > 0; o >>= 1) {
            if (t < o) red[t] += red[t + o];
            __syncthreads();
        }
        if (t == 0) out_ld[b * 3 + d] = red[0];
        __syncthreads();
    }
}

// ---------------- launch ----------------
extern "C" void kernel_launch(void* const* d_in, const int* in_sizes, int n_in,
                              void* d_out, int out_size, void* d_ws, size_t ws_size,
                              hipStream_t stream)
{
    const float* x         = (const float*)d_in[0];
    const float* scalar_l  = (const float*)d_in[1];
    const float* vec       = (const float*)d_in[2];
    const float* vector_l  = (const float*)d_in[3];
    const float* edge_feat = (const float*)d_in[4];
    const float* edge_ud   = (const float*)d_in[5];
    const int*   batch     = (const int*)d_in[6];
    const float* Wsg1 = (const float*)d_in[7];  const float* bsg1 = (const float*)d_in[8];
    const float* Wsg2 = (const float*)d_in[9];  const float* bsg2 = (const float*)d_in[10];
    const float* Wsl1 = (const float*)d_in[11]; const float* bsl1 = (const float*)d_in[12];
    const float* Wsl2 = (const float*)d_in[13]; const float* bsl2 = (const float*)d_in[14];
    const float* Wvg  = (const float*)d_in[15]; const float* Wvl  = (const float*)d_in[16];
    const float* Wxp1 = (const float*)d_in[17]; const float* bxp1 = (const float*)d_in[18];
    const float* Wxp2 = (const float*)d_in[19]; const float* bxp2 = (const float*)d_in[20];
    const float* Wep  = (const float*)d_in[21]; const float* bep  = (const float*)d_in[22];
    const float* Wvp  = (const float*)d_in[23];
    const float* Wlp1 = (const float*)d_in[24]; const float* blp1 = (const float*)d_in[25];
    const float* Wlp2 = (const float*)d_in[26]; const float* blp2 = (const float*)d_in[27];
    const float* Wml  = (const float*)d_in[28];

    const int N = in_sizes[0] / 128;
    const int B = in_sizes[1] / 128;

    float* out    = (float*)d_out;
    float* hx     = out;                                  // N*128  (xn, then hx)
    float* hv     = out + (size_t)N * 128;                // N*384  (vecn, then hvec)
    float* out_sl = hv + (size_t)N * 384;                 // B*128
    float* out_vl = out_sl + (size_t)B * 128;             // B*384
    float* out_ld = out_vl + (size_t)B * 384;             // B*3

    float* ws       = (float*)d_ws;
    float* SLW      = ws;                                 // B*128
    float* VLW      = SLW + (size_t)B * 128;              // B*384
    float* mean_x   = VLW + (size_t)B * 384;              // B*128
    float* mean_vec = mean_x + (size_t)B * 128;           // B*384

    k_precomp<<<dim3(B), dim3(128), 0, stream>>>(scalar_l, vector_l, Wsl1, bsl1, Wvl, SLW, VLW);
    k_node_a<<<dim3((N + 63) / 64), dim3(256), 0, stream>>>(x, vec, edge_feat, edge_ud,
                                                            Wxp1, bxp1, Wxp2, bxp2, Wep, bep, hx, hv, N);
    k_node_x<<<dim3((N + 63) / 64), dim3(256), 0, stream>>>(SLW, batch, Wsl1, Wsl2, bsl2, hx, N);
    k_node_v<<<dim3((N + 31) / 32), dim3(256), 0, stream>>>(VLW, batch, Wvl, hv, N);
    k_seg<<<dim3(B), dim3(256), 0, stream>>>(hx, hv, batch, mean_x, mean_vec, N);
    k_global<<<dim3(B), dim3(128), 0, stream>>>(mean_x, mean_vec, scalar_l, vector_l,
                                                Wsg1, bsg1, Wsg2, bsg2, Wvg, Wvp,
                                                Wlp1, blp1, Wlp2, blp2, Wml,
                                                out_sl, out_vl, out_ld);
}

// Round 4
// 1003.777 us; speedup vs baseline: 5.0108x; 1.2589x over previous
//
#include <hip/hip_runtime.h>
#include <math.h>

// ---------------- constants ----------------
#define SCALE_SSILU (1.0f / 0.6f)
#define INV3 0.57735026918962576451f   // 1/sqrt(3)
#define INVH 0.08838834764831844055f   // 1/sqrt(128)
#define AST 132                         // LDS activation row stride (floats)
#define EST 68

typedef __attribute__((ext_vector_type(4))) float  f32x4;
typedef __attribute__((ext_vector_type(8))) short  short8;

// frag-buffer offsets in uint4 units (hi/lo bf16 B-fragments, frag-linear)
#define FB_XP1 0
#define FB_XP2 4096
#define FB_EP  16384
#define FB_SL1 22528
#define FB_SL2 26624
#define FB_VL  30720
// total 34816 uint4 = 557056 B

__device__ __forceinline__ float ssilu(float v) {
    return v * SCALE_SSILU / (1.0f + __expf(-v));
}
__device__ __forceinline__ unsigned short bf16_rne(float x) {
    unsigned u = __float_as_uint(x);
    unsigned r = u + 0x7FFFu + ((u >> 16) & 1u);
    return (unsigned short)(r >> 16);
}

// split 8 consecutive fp32 (from LDS row) into hi/lo bf16x8 fragments
__device__ __forceinline__ void afrag_split(const float* __restrict__ Arow, short8& ah, short8& al) {
    float v[8];
    *(float4*)&v[0] = *(const float4*)&Arow[0];
    *(float4*)&v[4] = *(const float4*)&Arow[4];
#pragma unroll
    for (int j = 0; j < 8; ++j) {
        unsigned short h = bf16_rne(v[j]);
        ah[j] = (short)h;
        al[j] = (short)bf16_rne(v[j] - __uint_as_float((unsigned)h << 16));
    }
}

// D(16 rows x 128 cols) += A(16xK) @ W(Kx128-section), K = KC*32.
// Arow = &A_lds[(lane&15)*stride]; fb = u16 frag buffer; wbase in uint4 units; ct0 = first col-tile.
template<int KC, int CT>
__device__ __forceinline__ void mfma_gemm(const float* __restrict__ Arow,
                                          const unsigned short* __restrict__ fb,
                                          long wbase, int ct0, int l, f32x4 acc[8]) {
    const int g = l >> 4;
#pragma unroll
    for (int kc = 0; kc < KC; ++kc) {
        short8 ah, al;
        afrag_split(Arow + kc * 32 + g * 8, ah, al);
#pragma unroll
        for (int c = 0; c < 8; ++c) {
            const long fi = wbase + (long)((kc * CT + ct0 + c) * 2) * 64 + l;
            const short8 bh = *reinterpret_cast<const short8*>(fb + fi * 8);
            const short8 bl = *reinterpret_cast<const short8*>(fb + fi * 8 + 512);
            acc[c] = __builtin_amdgcn_mfma_f32_16x16x32_bf16(ah, bh, acc[c], 0, 0, 0);
            acc[c] = __builtin_amdgcn_mfma_f32_16x16x32_bf16(ah, bl, acc[c], 0, 0, 0);
            acc[c] = __builtin_amdgcn_mfma_f32_16x16x32_bf16(al, bh, acc[c], 0, 0, 0);
        }
    }
}

// stage 16 rows x 128 cols (row-major, stride 128) into per-wave LDS (stride AST)
__device__ __forceinline__ void stage16x128(const float* __restrict__ src, long rowbase, long rowmax,
                                            float* __restrict__ dst, int l) {
#pragma unroll
    for (int p = 0; p < 8; ++p) {
        const int idx = l + 64 * p;
        const int r = idx >> 5, c = (idx & 31) * 4;
        long row = rowbase + r; if (row > rowmax) row = rowmax;
        *(float4*)&dst[r * AST + c] = *(const float4*)&src[row * 128 + c];
    }
}

// ---------------- kernel W: weight -> split-bf16 frag-linear layout ----------------
__global__ __launch_bounds__(256) void k_wprep(
    const float* __restrict__ Wxp1, const float* __restrict__ Wxp2, const float* __restrict__ Wep,
    const float* __restrict__ Wsl1, const float* __restrict__ Wsl2, const float* __restrict__ Wvl,
    unsigned short* __restrict__ fb)
{
    const int e = blockIdx.x * 256 + threadIdx.x;
    const float* W; int LD, CT; long base; int off;
    if      (e < 16384)  { W = Wxp1; LD = 128; CT = 8;  base = FB_XP1; off = e; }
    else if (e < 65536)  { W = Wxp2; LD = 384; CT = 24; base = FB_XP2; off = e - 16384; }
    else if (e < 90112)  { W = Wep;  LD = 384; CT = 24; base = FB_EP;  off = e - 65536; }
    else if (e < 106496) { W = Wsl1; LD = 128; CT = 8;  base = FB_SL1; off = e - 90112; }
    else if (e < 122880) { W = Wsl2; LD = 128; CT = 8;  base = FB_SL2; off = e - 106496; }
    else if (e < 139264) { W = Wvl;  LD = 128; CT = 8;  base = FB_VL;  off = e - 122880; }
    else return;
    const int frag = off >> 9;
    const int l = (off >> 3) & 63;
    const int j = off & 7;
    const int kc = frag / CT, ct = frag - kc * CT;
    const int k = kc * 32 + ((l >> 4) << 3) + j;
    const int col = ct * 16 + (l & 15);
    const float x = W[(long)k * LD + col];
    const unsigned short h = bf16_rne(x);
    const unsigned short lo = bf16_rne(x - __uint_as_float((unsigned)h << 16));
    const long fbase = (base + (long)frag * 128) * 8;   // uint4->u16 index
    fb[fbase + (long)l * 8 + j] = h;
    fb[fbase + 512 + (long)l * 8 + j] = lo;
}

// ---------------- kernel 0: per-batch precompute (fp32, tiny) ----------------
__global__ __launch_bounds__(128) void k_precomp(
    const float* __restrict__ scalar_l, const float* __restrict__ vector_l,
    const float* __restrict__ Wsl1, const float* __restrict__ bsl1,
    const float* __restrict__ Wvl,
    float* __restrict__ SLW, float* __restrict__ VLW)
{
    const int b = blockIdx.x, t = threadIdx.x;
    __shared__ float sl[128];
    __shared__ float vl[3 * 128];
    sl[t] = scalar_l[b * 128 + t];
    for (int d = 0; d < 3; ++d) vl[d * 128 + t] = vector_l[b * 384 + d * 128 + t];
    __syncthreads();
    float acc = bsl1[t];
    for (int k = 0; k < 128; ++k) acc = fmaf(sl[k], Wsl1[(128 + k) * 128 + t], acc);
    SLW[b * 128 + t] = acc;
    for (int d = 0; d < 3; ++d) {
        float a = 0.f;
        for (int k = 0; k < 128; ++k) a = fmaf(vl[d * 128 + k], Wvl[k * 128 + t], a);
        VLW[b * 384 + d * 128 + t] = a;
    }
}

// ---------------- kernel 1: node part A (MFMA, 64 rows/block, 16/wave, no barriers) -----------
__global__ __launch_bounds__(256) void k_node_a(
    const float* __restrict__ x, const float* __restrict__ vec,
    const float* __restrict__ ef, const float* __restrict__ udiff,
    const float* __restrict__ bxp1, const float* __restrict__ bxp2, const float* __restrict__ bep,
    const unsigned short* __restrict__ fb,
    float* __restrict__ xn_out, float* __restrict__ vecn_out, int N)
{
    __shared__ float Ash[4 * 16 * AST];
    __shared__ float Esh[4 * 16 * EST];
    const int t = threadIdx.x, l = t & 63, w = t >> 6;
    const int m = l & 15, g = l >> 4;
    float* Axs = Ash + w * (16 * AST);
    float* Efs = Esh + w * (16 * EST);
    const long nb = (long)blockIdx.x * 64 + w * 16;
    const long nmax = (long)N - 1;

    stage16x128(x, nb, nmax, Axs, l);
#pragma unroll
    for (int p = 0; p < 4; ++p) {
        const int idx = l + 64 * p;
        const int r = idx >> 4, c = (idx & 15) * 4;
        long row = nb + r; if (row > nmax) row = nmax;
        *(float4*)&Efs[r * EST + c] = *(const float4*)&ef[row * 64 + c];
    }
    const float* Arow = Axs + m * AST;
    const float* Erow = Efs + m * EST;

    // ---- phase A: t1 = ssilu(x @ Wxp1 + b) ----
    f32x4 acc[8];
#pragma unroll
    for (int c = 0; c < 8; ++c) { const float bv = bxp1[c * 16 + m]; acc[c] = (f32x4){bv, bv, bv, bv}; }
    mfma_gemm<4, 8>(Arow, fb, FB_XP1, 0, l, acc);

    // save x residual (D layout), then overwrite x with t1 (in-wave DS ordering)
    float xres[8][4];
#pragma unroll
    for (int c = 0; c < 8; ++c)
#pragma unroll
        for (int i = 0; i < 4; ++i) xres[c][i] = Axs[(g * 4 + i) * AST + c * 16 + m];
#pragma unroll
    for (int c = 0; c < 8; ++c)
#pragma unroll
        for (int i = 0; i < 4; ++i) Axs[(g * 4 + i) * AST + c * 16 + m] = ssilu(acc[c][i]);

    // ---- one third: p_j = (t1@Wxp2_j + b) * (ef@Wep_j + b) * inv_sqrt3 ----
    f32x4 px[8], pe[8];
    auto do_third = [&](int j) {
#pragma unroll
        for (int c = 0; c < 8; ++c) {
            const float bx = bxp2[j * 128 + c * 16 + m];
            const float be = bep [j * 128 + c * 16 + m];
            px[c] = (f32x4){bx, bx, bx, bx};
            pe[c] = (f32x4){be, be, be, be};
        }
        mfma_gemm<4, 24>(Arow, fb, FB_XP2, j * 8, l, px);
        mfma_gemm<2, 24>(Erow, fb, FB_EP,  j * 8, l, pe);
#pragma unroll
        for (int c = 0; c < 8; ++c) px[c] = px[c] * pe[c] * INV3;
    };

    // j=2 first: xn = p3 + x
    do_third(2);
#pragma unroll
    for (int i = 0; i < 4; ++i) {
        const long row = nb + g * 4 + i;
        if (row < (long)N) {
#pragma unroll
            for (int c = 0; c < 8; ++c)
                xn_out[row * 128 + c * 16 + m] = px[c][i] + xres[c][i];
        }
    }
    // j=0: p1
    do_third(0);
    f32x4 p1[8];
#pragma unroll
    for (int c = 0; c < 8; ++c) p1[c] = px[c];
    // j=1: p2, then vecn = (p1*vec + p2*ud)/sqrt(128)
    do_third(1);
#pragma unroll
    for (int i = 0; i < 4; ++i) {
        const long row = nb + g * 4 + i;
        if (row < (long)N) {
            const float u0 = udiff[row * 3 + 0], u1 = udiff[row * 3 + 1], u2 = udiff[row * 3 + 2];
#pragma unroll
            for (int d = 0; d < 3; ++d) {
                const float ud = (d == 0) ? u0 : (d == 1) ? u1 : u2;
                const long vb = (row * 3 + d) * 128;
#pragma unroll
                for (int c = 0; c < 8; ++c) {
                    const float v = vec[vb + c * 16 + m];
                    vecn_out[vb + c * 16 + m] = fmaf(p1[c][i], v, px[c][i] * ud) * INVH;
                }
            }
        }
    }
}

// ---------------- kernel 2a: hx (MFMA, in-place over xn region) ----------------
__global__ __launch_bounds__(256) void k_node_x(
    const float* __restrict__ SLW, const int* __restrict__ batch,
    const float* __restrict__ bsl2, const unsigned short* __restrict__ fb,
    float* __restrict__ hx, int N)
{
    __shared__ float Ash[4 * 16 * AST];
    const int t = threadIdx.x, l = t & 63, w = t >> 6;
    const int m = l & 15, g = l >> 4;
    float* Axs = Ash + w * (16 * AST);
    const long nb = (long)blockIdx.x * 64 + w * 16;
    const long nmax = (long)N - 1;

    stage16x128(hx, nb, nmax, Axs, l);

    int bi[4];
#pragma unroll
    for (int i = 0; i < 4; ++i) { long r = nb + g * 4 + i; if (r > nmax) r = nmax; bi[i] = batch[r]; }

    const float* Arow = Axs + m * AST;

    // residual (D layout) before overwrite
    float xres[8][4];
#pragma unroll
    for (int c = 0; c < 8; ++c)
#pragma unroll
        for (int i = 0; i < 4; ++i) xres[c][i] = Axs[(g * 4 + i) * AST + c * 16 + m];

    // GEMM1: t = ssilu(xn @ Wsl1[:128] + SLW[batch])
    f32x4 acc[8];
#pragma unroll
    for (int c = 0; c < 8; ++c)
#pragma unroll
        for (int i = 0; i < 4; ++i) acc[c][i] = SLW[(long)bi[i] * 128 + c * 16 + m];
    mfma_gemm<4, 8>(Arow, fb, FB_SL1, 0, l, acc);
#pragma unroll
    for (int c = 0; c < 8; ++c)
#pragma unroll
        for (int i = 0; i < 4; ++i) Axs[(g * 4 + i) * AST + c * 16 + m] = ssilu(acc[c][i]);

    // GEMM2: hx = ssilu(t @ Wsl2 + b2) + xn
#pragma unroll
    for (int c = 0; c < 8; ++c) { const float bv = bsl2[c * 16 + m]; acc[c] = (f32x4){bv, bv, bv, bv}; }
    mfma_gemm<4, 8>(Arow, fb, FB_SL2, 0, l, acc);
#pragma unroll
    for (int i = 0; i < 4; ++i) {
        const long row = nb + g * 4 + i;
        if (row < (long)N) {
#pragma unroll
            for (int c = 0; c < 8; ++c)
                hx[row * 128 + c * 16 + m] = ssilu(acc[c][i]) + xres[c][i];
        }
    }
}

// ---------------- kernel 2b: hvec (MFMA, flat rows = 3N, in-place) ----------------
__global__ __launch_bounds__(256) void k_node_v(
    const float* __restrict__ VLW, const int* __restrict__ batch,
    const unsigned short* __restrict__ fb,
    float* __restrict__ hv, int N)
{
    __shared__ float Ash[4 * 16 * AST];
    const int t = threadIdx.x, l = t & 63, w = t >> 6;
    const int m = l & 15, g = l >> 4;
    float* Axs = Ash + w * (16 * AST);
    const long R = (long)N * 3;
    const long rb = (long)blockIdx.x * 64 + w * 16;

    stage16x128(hv, rb, R - 1, Axs, l);

    f32x4 acc[8];
#pragma unroll
    for (int i = 0; i < 4; ++i) {
        long row = rb + g * 4 + i; if (row > R - 1) row = R - 1;
        const long node = row / 3;
        const int dd = (int)(row - node * 3);
        const int b = batch[node];
        const long vwb = (long)b * 384 + dd * 128;
#pragma unroll
        for (int c = 0; c < 8; ++c) acc[c][i] = VLW[vwb + c * 16 + m];
    }
    const float* Arow = Axs + m * AST;
    mfma_gemm<4, 8>(Arow, fb, FB_VL, 0, l, acc);
#pragma unroll
    for (int i = 0; i < 4; ++i) {
        const long row = rb + g * 4 + i;
        if (row < R) {
#pragma unroll
            for (int c = 0; c < 8; ++c)
                hv[row * 128 + c * 16 + m] = acc[c][i] + Axs[(g * 4 + i) * AST + c * 16 + m];
        }
    }
}

// ---------------- kernel 3: segment means ----------------
__device__ __forceinline__ int lbound(const int* __restrict__ a, int n, int v) {
    int lo = 0, hi = n;
    while (lo < hi) { int mm = (lo + hi) >> 1; if (a[mm] < v) lo = mm + 1; else hi = mm; }
    return lo;
}
__global__ __launch_bounds__(256) void k_seg(
    const float* __restrict__ hx, const float* __restrict__ hv,
    const int* __restrict__ batch,
    float* __restrict__ mean_x, float* __restrict__ mean_vec, int N)
{
    const int b = blockIdx.x, t = threadIdx.x;
    const int s = lbound(batch, N, b);
    const int e = lbound(batch, N, b + 1);
    float a0 = 0.f, a1 = 0.f, a2 = 0.f, a3 = 0.f;
    float c0 = 0.f, c1 = 0.f, c2 = 0.f, c3 = 0.f;
    int i = s;
    for (; i + 4 <= e; i += 4) {
        float v0, v1, v2, v3;
        if (t < 128) {
            v0 = hx[(long)(i + 0) * 128 + t]; v1 = hx[(long)(i + 1) * 128 + t];
            v2 = hx[(long)(i + 2) * 128 + t]; v3 = hx[(long)(i + 3) * 128 + t];
        } else {
            v0 = hv[(long)(i + 0) * 384 + (t - 128)]; v1 = hv[(long)(i + 1) * 384 + (t - 128)];
            v2 = hv[(long)(i + 2) * 384 + (t - 128)]; v3 = hv[(long)(i + 3) * 384 + (t - 128)];
        }
        a0 += v0; a1 += v1; a2 += v2; a3 += v3;
        c0 += hv[(long)(i + 0) * 384 + t + 128]; c1 += hv[(long)(i + 1) * 384 + t + 128];
        c2 += hv[(long)(i + 2) * 384 + t + 128]; c3 += hv[(long)(i + 3) * 384 + t + 128];
    }
    for (; i < e; ++i) {
        a0 += (t < 128) ? hx[(long)i * 128 + t] : hv[(long)i * 384 + (t - 128)];
        c0 += hv[(long)i * 384 + t + 128];
    }
    const float acc0 = (a0 + a1) + (a2 + a3);
    const float acc1 = (c0 + c1) + (c2 + c3);
    int cnt = e - s; if (cnt < 1) cnt = 1;
    const float inv = 1.0f / (float)cnt;
    if (t < 128) mean_x[b * 128 + t] = acc0 * inv;
    else         mean_vec[b * 384 + (t - 128)] = acc0 * inv;
    mean_vec[b * 384 + t + 128] = acc1 * inv;
}

// ---------------- kernel 4: global tail (B rows, fp32) ----------------
__global__ __launch_bounds__(128) void k_global(
    const float* __restrict__ mean_x, const float* __restrict__ mean_vec,
    const float* __restrict__ scalar_l, const float* __restrict__ vector_l,
    const float* __restrict__ Wsg1, const float* __restrict__ bsg1,
    const float* __restrict__ Wsg2, const float* __restrict__ bsg2,
    const float* __restrict__ Wvg, const float* __restrict__ Wvp,
    const float* __restrict__ Wlp1, const float* __restrict__ blp1,
    const float* __restrict__ Wlp2, const float* __restrict__ blp2,
    const float* __restrict__ Wml,
    float* __restrict__ out_sl, float* __restrict__ out_vl, float* __restrict__ out_ld)
{
    const int b = blockIdx.x, t = threadIdx.x;
    __shared__ float g[256];
    __shared__ float mv[384];
    __shared__ float sl[128];
    __shared__ float vl[384];
    __shared__ float h1[384];
    __shared__ float vnorm[128];
    __shared__ float t2[128];
    __shared__ float red[128];

    g[t] = mean_x[b * 128 + t];
    const float slin = scalar_l[b * 128 + t];
    g[128 + t] = slin;
    for (int d = 0; d < 3; ++d)
        mv[d * 128 + t] = mean_vec[b * 384 + d * 128 + t] + vector_l[b * 384 + d * 128 + t];
    __syncthreads();

    float acc = bsg1[t];
    for (int k = 0; k < 256; ++k) acc = fmaf(g[k], Wsg1[k * 128 + t], acc);
    const float tA = ssilu(acc);
    __syncthreads();
    g[t] = tA;
    __syncthreads();

    acc = bsg2[t];
    for (int k = 0; k < 128; ++k) acc = fmaf(g[k], Wsg2[k * 128 + t], acc);
    sl[t] = slin + ssilu(acc);
    for (int d = 0; d < 3; ++d) {
        float a = 0.f;
        for (int k = 0; k < 128; ++k) a = fmaf(mv[d * 128 + k], Wvg[k * 128 + t], a);
        vl[d * 128 + t] = vector_l[b * 384 + d * 128 + t] + a;
    }
    __syncthreads();

    float hh0 = 0.f, hh1 = 0.f, hh2 = 0.f;
    for (int d = 0; d < 3; ++d) {
        float a1 = 0.f, a2 = 0.f;
        for (int k = 0; k < 128; ++k) {
            const float v = vl[d * 128 + k];
            a1 = fmaf(v, Wvp[k * 256 + t], a1);
            a2 = fmaf(v, Wvp[k * 256 + 128 + t], a2);
        }
        h1[d * 128 + t] = a1;
        if (d == 0) hh0 = a2; else if (d == 1) hh1 = a2; else hh2 = a2;
    }
    vnorm[t] = sqrtf(hh0 * hh0 + hh1 * hh1 + hh2 * hh2 + 1e-8f);
    __syncthreads();

    acc = blp1[t];
    for (int k = 0; k < 128; ++k) acc = fmaf(sl[k], Wlp1[k * 128 + t], acc);
    for (int k = 0; k < 128; ++k) acc = fmaf(vnorm[k], Wlp1[(128 + k) * 128 + t], acc);
    t2[t] = ssilu(acc);
    __syncthreads();

    float s1 = blp2[t], s2 = blp2[128 + t], s3 = blp2[256 + t];
    for (int k = 0; k < 128; ++k) {
        const float v = t2[k];
        s1 = fmaf(v, Wlp2[k * 384 + t], s1);
        s2 = fmaf(v, Wlp2[k * 384 + 128 + t], s2);
        s3 = fmaf(v, Wlp2[k * 384 + 256 + t], s3);
    }
    out_sl[b * 128 + t] = s2 + sl[t] * tanhf(s3);

    const float wm = Wml[t];
    for (int d = 0; d < 3; ++d) {
        const float vo = fmaf(s1, h1[d * 128 + t], vl[d * 128 + t]);
        out_vl[b * 384 + d * 128 + t] = vo;
        red[t] = vo * wm;
        __syncthreads();
        for (int o = 64; o > 0; o >>= 1) {
            if (t < o) red[t] += red[t + o];
            __syncthreads();
        }
        if (t == 0) out_ld[b * 3 + d] = red[0];
        __syncthreads();
    }
}

// ---------------- launch ----------------
extern "C" void kernel_launch(void* const* d_in, const int* in_sizes, int n_in,
                              void* d_out, int out_size, void* d_ws, size_t ws_size,
                              hipStream_t stream)
{
    const float* x         = (const float*)d_in[0];
    const float* scalar_l  = (const float*)d_in[1];
    const float* vec       = (const float*)d_in[2];
    const float* vector_l  = (const float*)d_in[3];
    const float* edge_feat = (const float*)d_in[4];
    const float* edge_ud   = (const float*)d_in[5];
    const int*   batch     = (const int*)d_in[6];
    const float* Wsg1 = (const float*)d_in[7];  const float* bsg1 = (const float*)d_in[8];
    const float* Wsg2 = (const float*)d_in[9];  const float* bsg2 = (const float*)d_in[10];
    const float* Wsl1 = (const float*)d_in[11]; const float* bsl1 = (const float*)d_in[12];
    const float* Wsl2 = (const float*)d_in[13]; const float* bsl2 = (const float*)d_in[14];
    const float* Wvg  = (const float*)d_in[15]; const float* Wvl  = (const float*)d_in[16];
    const float* Wxp1 = (const float*)d_in[17]; const float* bxp1 = (const float*)d_in[18];
    const float* Wxp2 = (const float*)d_in[19]; const float* bxp2 = (const float*)d_in[20];
    const float* Wep  = (const float*)d_in[21]; const float* bep  = (const float*)d_in[22];
    const float* Wvp  = (const float*)d_in[23];
    const float* Wlp1 = (const float*)d_in[24]; const float* blp1 = (const float*)d_in[25];
    const float* Wlp2 = (const float*)d_in[26]; const float* blp2 = (const float*)d_in[27];
    const float* Wml  = (const float*)d_in[28];

    const int N = in_sizes[0] / 128;
    const int B = in_sizes[1] / 128;

    float* out    = (float*)d_out;
    float* hx     = out;                                  // N*128  (xn, then hx)
    float* hv     = out + (size_t)N * 128;                // N*384  (vecn, then hvec)
    float* out_sl = hv + (size_t)N * 384;                 // B*128
    float* out_vl = out_sl + (size_t)B * 128;             // B*384
    float* out_ld = out_vl + (size_t)B * 384;             // B*3

    float* ws       = (float*)d_ws;
    float* SLW      = ws;                                 // B*128
    float* VLW      = SLW + (size_t)B * 128;              // B*384
    float* mean_x   = VLW + (size_t)B * 384;              // B*128
    float* mean_vec = mean_x + (size_t)B * 128;           // B*384
    unsigned short* fb = (unsigned short*)(mean_vec + (size_t)B * 384);  // 557056 B

    k_wprep<<<dim3(544), dim3(256), 0, stream>>>(Wxp1, Wxp2, Wep, Wsl1, Wsl2, Wvl, fb);
    k_precomp<<<dim3(B), dim3(128), 0, stream>>>(scalar_l, vector_l, Wsl1, bsl1, Wvl, SLW, VLW);
    k_node_a<<<dim3((N + 63) / 64), dim3(256), 0, stream>>>(x, vec, edge_feat, edge_ud,
                                                            bxp1, bxp2, bep, fb, hx, hv, N);
    k_node_x<<<dim3((N + 63) / 64), dim3(256), 0, stream>>>(SLW, batch, bsl2, fb, hx, N);
    k_node_v<<<dim3((3 * N + 63) / 64), dim3(256), 0, stream>>>(VLW, batch, fb, hv, N);
    k_seg<<<dim3(B), dim3(256), 0, stream>>>(hx, hv, batch, mean_x, mean_vec, N);
    k_global<<<dim3(B), dim3(128), 0, stream>>>(mean_x, mean_vec, scalar_l, vector_l,
                                                Wsg1, bsg1, Wsg2, bsg2, Wvg, Wvp,
                                                Wlp1, blp1, Wlp2, blp2, Wml,
                                                out_sl, out_vl, out_ld);
}